// Round 5
// baseline (320.046 us; speedup 1.0000x reference)
//
#include <hip/hip_runtime.h>

// Problem constants (from reference)
#define R_MAX 32
#define S_MAX 2
#define C_Z   128
#define NTB   67                     // 2*R_MAX + 2 + 1
#define IN_DIM 141                   // 2*NTB + (2*S_MAX+2) + 1
#define JT   256                     // j-tile width per block
#define IR   2                       // i-rows per block
#define TROWS 48                     // precomputed combo-table rows

typedef float vf4 __attribute__((ext_vector_type(4)));

__device__ __forceinline__ int clampi(int x, int lo, int hi) {
    return min(max(x, lo), hi);
}

// Combo table (48 rows x 128 ch), indexed r = cls*12 + g, g = se*6 + dc:
//  cls 0: W_res[66]+W_tok[66] + se*w_ent + W_chain[dc]   (masked pairs)
//  cls 1: W_res[65]+W_tok[65] + se*w_ent + W_chain[dc]   (different chain)
//  cls 2: W_tok[65]           + se*w_ent + W_chain[dc]   (+ W_res[dr] gather)
//  cls 3: W_res[32]           + se*w_ent + W_chain[dc]   (+ W_tok[dt] gather)
__device__ __forceinline__ vf4 table_entry(const vf4* __restrict__ W4, int r, int c) {
    int g  = r % 12, cls = r / 12;
    int se = g / 6,  dc  = g % 6;
    vf4 v;
    if (cls == 0)      v = W4[66*32 + c] + W4[(NTB + 66)*32 + c];
    else if (cls == 1) v = W4[65*32 + c] + W4[(NTB + 65)*32 + c];
    else if (cls == 2) v = W4[(NTB + 65)*32 + c];
    else               v = W4[32*32 + c];
    v = v + W4[(2*NTB + 1 + dc)*32 + c];
    if (se) v = v + W4[(2*NTB)*32 + c];
    return v;
}

// Pre-kernel: materialize the 48x128 combo table into workspace (24 KB).
__global__ __launch_bounds__(256) void table_kernel(const float* __restrict__ W,
                                                    float* __restrict__ ws) {
    int idx = blockIdx.x * 256 + threadIdx.x;        // 0..1535 (48 rows x 32 chunks)
    ((vf4*)ws)[idx] = table_entry((const vf4*)W, idx >> 5, idx & 31);
}

// Grid: (ceil(N/JT), ceil(B*N/IR)). Block: 256.
// Phase 0: combo table ws -> LDS (24 KB).
// Phase 1: classify IR*256 pairs into (lds_row, gather_row) codes (LDS, transposed).
// Phase 2: per pair: 1 ds_read_b128 + rare (12.5%) global gather + 1 float4 store.
__global__ __launch_bounds__(256) void relpos_kernel(
    const int* __restrict__ asym, const int* __restrict__ ent,
    const int* __restrict__ res,  const int* __restrict__ tok,
    const int* __restrict__ sym,  const int* __restrict__ mask,
    const float* __restrict__ W,  const float* __restrict__ ws,
    float* __restrict__ out, int N, int BN, int use_ws)
{
    __shared__ vf4 table_s[TROWS * 32];              // 24 KB
    __shared__ __align__(16) int codeT[IR * JT];     // 2 KB, transposed per i-row

    const int tid  = threadIdx.x;
    const int jb   = blockIdx.x * JT;
    const int row0 = blockIdx.y * IR;
    const vf4* __restrict__ W4 = (const vf4*)W;

    // ---- Phase 0: stage combo table ----
    if (use_ws) {
        const vf4* __restrict__ ws4 = (const vf4*)ws;
        #pragma unroll
        for (int k = 0; k < 6; ++k) { int idx = tid + k*256; table_s[idx] = ws4[idx]; }
    } else {
        #pragma unroll
        for (int k = 0; k < 6; ++k) { int idx = tid + k*256; table_s[idx] = table_entry(W4, idx >> 5, idx & 31); }
    }

    // ---- Phase 1: classify pairs ----
    {
        int j = jb + tid;
        bool jok = (j < N);
        for (int ir = 0; ir < IR; ++ir) {
            int row = row0 + ir;
            int code = 0;
            if (jok && row < BN) {
                int b    = row / N;
                int jrow = b * N + j;
                int aj = asym[jrow], ej = ent[jrow], rj = res[jrow], tj = tok[jrow], sj = sym[jrow];
                int ai = asym[row],  ei = ent[row],  ri = res[row],  ti = tok[row],  si = sym[row];
                bool sc = (ai == aj), sent = (ei == ej), sr = (ri == rj);
                int dc = sent ? clampi(si - sj + S_MAX, 0, 2*S_MAX) : (2*S_MAX + 1);
                int g  = (sent ? 6 : 0) + dc;
                bool m = mask[(long long)row * N + j] != 0;
                int lrow, grow;
                if (m)        { lrow = g;        grow = 0; }
                else if (!sc) { lrow = 12 + g;   grow = 0; }
                else if (!sr) { lrow = 24 + g;   grow = 1 + clampi(ri - rj + R_MAX, 0, 2*R_MAX); }
                else          { lrow = 36 + g;   grow = 1 + NTB + clampi(ti - tj + R_MAX, 0, 2*R_MAX); }
                code = lrow | (grow << 6);
            }
            codeT[ir * JT + (tid & 7) * 32 + (tid >> 3)] = code;
        }
    }
    __syncthreads();

    // ---- Phase 2: stream output ----
    const int chunk = tid & 31;
    const int psub  = tid >> 5;
    const int jmax  = min(JT, N - jb);

    for (int ir = 0; ir < IR; ++ir) {
        int row = row0 + ir;
        if (row >= BN) break;
        vf4* __restrict__ outp = (vf4*)out + ((long long)row * N + jb) * 32 + chunk;

        int4 creg[8];
        const int4* cp = (const int4*)&codeT[ir * JT + psub * 32];
        #pragma unroll
        for (int k = 0; k < 8; ++k) creg[k] = cp[k];         // ds_read_b128 broadcasts

#define PROC(codev, itv)                                                      \
        {                                                                     \
            int code = (codev);                                               \
            int pair = (itv) * 8 + psub;                                      \
            int lrow = code & 63;                                             \
            int grow = code >> 6;                                             \
            vf4 acc  = table_s[lrow * 32 + chunk];                            \
            if (grow) acc += W4[(grow - 1) * 32 + chunk];                     \
            outp[pair * 32] = acc;                                            \
        }

        if (jmax == JT) {
            #pragma unroll
            for (int k = 0; k < 8; ++k) {
                int4 c = creg[k];
                PROC(c.x, 4*k + 0)
                PROC(c.y, 4*k + 1)
                PROC(c.z, 4*k + 2)
                PROC(c.w, 4*k + 3)
            }
        } else {
            #pragma unroll
            for (int k = 0; k < 8; ++k) {
                int4 c = creg[k];
                if (4*k*8 + psub < jmax)       PROC(c.x, 4*k + 0)
                if ((4*k + 1)*8 + psub < jmax) PROC(c.y, 4*k + 1)
                if ((4*k + 2)*8 + psub < jmax) PROC(c.z, 4*k + 2)
                if ((4*k + 3)*8 + psub < jmax) PROC(c.w, 4*k + 3)
            }
        }
#undef PROC
    }
}

extern "C" void kernel_launch(void* const* d_in, const int* in_sizes, int n_in,
                              void* d_out, int out_size, void* d_ws, size_t ws_size,
                              hipStream_t stream) {
    const int*   asym = (const int*)d_in[0];
    const int*   ent  = (const int*)d_in[1];
    const int*   res  = (const int*)d_in[2];
    const int*   tok  = (const int*)d_in[3];
    const int*   sym  = (const int*)d_in[4];
    const int*   mask = (const int*)d_in[5];
    const float* W    = (const float*)d_in[6];
    float*       out  = (float*)d_out;

    long long BN      = in_sizes[0];        // B*N
    long long mask_sz = in_sizes[5];        // B*N*N
    int N = (int)(mask_sz / BN);

    int use_ws = (ws_size >= (size_t)(TROWS * 32 * sizeof(vf4))) ? 1 : 0;  // 24 KB
    if (use_ws) {
        table_kernel<<<6, 256, 0, stream>>>(W, (float*)d_ws);
    }

    dim3 grid((unsigned)((N + JT - 1) / JT), (unsigned)((BN + IR - 1) / IR));
    relpos_kernel<<<grid, 256, 0, stream>>>(
        asym, ent, res, tok, sym, mask, W, (const float*)d_ws, out,
        N, (int)BN, use_ws);
}